// Round 3
// baseline (388.422 us; speedup 1.0000x reference)
//
#include <hip/hip_runtime.h>

// Problem constants
#define NN 64
#define CC 64
#define TT 256
#define VV 25
#define RR 8
#define OO 64
#define PLANE 6400  // T*V per (n,c)

// ---------------------------------------------------------------------------
// Kernel A: xsum[n][c][v] = sum_t x[n][c][t][v]
// One block per (n,c). Coalesced LDS staging (25 x 256 dwords), then a
// parallel 8-chunk x 32-t tree reduction (stride-25 reads: 25 consecutive
// lanes -> consecutive addrs; second half-wave offset 800 = 0 mod 32 -> 2-way
// aliasing only, which is free).
// ---------------------------------------------------------------------------
__global__ __launch_bounds__(256) void k_xsum(const float* __restrict__ x,
                                              float* __restrict__ xsum) {
  int nc = blockIdx.x;  // n*64 + c
  const float* src = x + (size_t)nc * PLANE;
  __shared__ float s[PLANE];
  __shared__ float ps[8][33];
  int tid = threadIdx.x;
#pragma unroll
  for (int k = 0; k < 25; ++k) s[k * 256 + tid] = src[k * 256 + tid];
  __syncthreads();
  int v = tid & 31, chunk = tid >> 5;
  if (v < VV) {
    float a = 0.f;
#pragma unroll
    for (int i = 0; i < 32; ++i) a += s[(chunk * 32 + i) * VV + v];
    ps[chunk][v] = a;
  }
  __syncthreads();
  if (tid < VV) {
    float a = 0.f;
#pragma unroll
    for (int c = 0; c < 8; ++c) a += ps[c][tid];
    xsum[nc * VV + tid] = a;
  }
}

// ---------------------------------------------------------------------------
// Kernel B: build m (padded [n][o][u][32]) from xsum; also emit w3t[c][o].
// ---------------------------------------------------------------------------
__global__ __launch_bounds__(256) void k_build_m(
    const float* __restrict__ xsum, const float* __restrict__ A,
    const float* __restrict__ w1, const float* __restrict__ b1,
    const float* __restrict__ w2, const float* __restrict__ b2,
    const float* __restrict__ w4, const float* __restrict__ b4,
    const float* __restrict__ w3, float* __restrict__ w3t,
    float* __restrict__ mp) {
  int n = blockIdx.x;
  __shared__ float xs[CC * VV];    // 1600
  __shared__ float sx1[RR * VV];   // 200
  __shared__ float sx2[RR * VV];   // 200
  __shared__ float att[RR * 625];  // 5000
  int tid = threadIdx.x;
  // w3 transpose (all 64 blocks write identical values - benign)
  for (int k = tid; k < CC * OO; k += 256) {
    int c = k >> 6, o = k & 63;
    w3t[k] = w3[o * CC + c];
  }
  const float* xsn = xsum + n * (CC * VV);
  for (int k = tid; k < CC * VV; k += 256) xs[k] = xsn[k];
  __syncthreads();
  if (tid < RR * VV) {
    int r = tid / VV, v = tid % VV;
    float a1 = 0.f, a2 = 0.f;
#pragma unroll
    for (int c = 0; c < CC; ++c) {
      float xv = xs[c * VV + v];
      a1 = fmaf(w1[r * CC + c], xv, a1);
      a2 = fmaf(w2[r * CC + c], xv, a2);
    }
    sx1[tid] = a1 * (1.f / 256.f) + b1[r];
    sx2[tid] = a2 * (1.f / 256.f) + b2[r];
  }
  __syncthreads();
  for (int k = tid; k < RR * 625; k += 256) {
    int r = k / 625, uv = k % 625;
    int u = uv / VV, v = uv % VV;
    att[k] = tanhf(sx1[r * VV + u] - sx2[r * VV + v]);
  }
  __syncthreads();
  for (int k = tid; k < OO * 625; k += 256) {
    int o = k / 625, uv = k % 625;
    int u = uv / VV, v = uv % VV;
    float a = b4[o] + A[uv];
#pragma unroll
    for (int r = 0; r < RR; ++r) a = fmaf(w4[o * RR + r], att[r * 625 + uv], a);
    mp[(((size_t)n * OO + o) * VV + u) * 32 + v] = a;
  }
}

// ---------------------------------------------------------------------------
// Kernel C (fused conv3 + aggregation), o-chunked to keep accumulators in
// VGPRs (32 acc + ~25 scratch < 85-VGPR budget from launch_bounds(832,6);
// round-2's acc[64] at VGPR_Count=52 forced AGPR round-trips -> 165us).
// Block = (n, 32-t tile), 832 threads (13 waves), thread <-> p=(t,v).
// For each half (32 o's): conv c-loop (x re-read on half 1 hits L2/LLC),
// then 3 rounds of 13 wave-uniform o's: deposit x3 slice to LDS, per-wave
// 25x25 GEMV with m via scalar loads, coalesced dump.
// ---------------------------------------------------------------------------
__global__ __launch_bounds__(832, 6) void k_fused(const float* __restrict__ x,
                                                  const float* __restrict__ w3t,
                                                  const float* __restrict__ b3,
                                                  const float* __restrict__ mp,
                                                  float* __restrict__ out) {
  int tile = blockIdx.x;  // 0..7  (t0 = tile*32)
  int n = blockIdx.y;     // 0..63
  int tid = threadIdx.x;
  int tidc = tid < 800 ? tid : 799;  // clamp padding threads (benign dup)
  int v = tidc % VV;
  int t_loc = tidc / VV;  // 0..31
  int wave = tid >> 6;    // 0..12
  int lane = tid & 63;

  __shared__ float s3[13][825];  // 42.9 KB

  const float* xn = x + (size_t)n * CC * PLANE + tile * 800;
  const float* mpn = mp + (size_t)n * OO * (VV * 32);

#pragma unroll
  for (int half = 0; half < 2; ++half) {
    // ---- conv for o in [half*32, half*32+32) ----
    float acc[32];
#pragma unroll
    for (int i = 0; i < 32; ++i) acc[i] = 0.f;
#pragma unroll 2
    for (int c = 0; c < CC; ++c) {
      float xv = xn[(size_t)c * PLANE + tidc];
      const float* w = w3t + c * OO + half * 32;  // wave-uniform -> s_load
#pragma unroll
      for (int i = 0; i < 32; ++i) acc[i] = fmaf(w[i], xv, acc[i]);
    }
    // ---- aggregation: 3 rounds of <=13 wave-uniform o's ----
#pragma unroll
    for (int r = 0; r < 3; ++r) {
      // deposit this round's x3 slices (compile-time acc indices)
#pragma unroll
      for (int wv = 0; wv < 13; ++wv) {
        int oi = r * 13 + wv;
        if (oi < 32) s3[wv][v * 33 + t_loc] = acc[oi] + b3[half * 32 + oi];
      }
      __syncthreads();
      int oi = r * 13 + wave;
      bool alive = (oi < 32);
      int o = half * 32 + oi;
      if (alive && lane < 32) {
        int ou = __builtin_amdgcn_readfirstlane(o);
        const float* mrow = mpn + (size_t)ou * (VV * 32);  // wave-uniform
        float xr[VV];
#pragma unroll
        for (int vv = 0; vv < VV; ++vv) xr[vv] = s3[wave][vv * 33 + lane];
#pragma unroll
        for (int u = 0; u < VV; ++u) {
          float a = 0.f;
#pragma unroll
          for (int vv = 0; vv < VV; ++vv)
            a = fmaf(mrow[u * 32 + vv], xr[vv], a);
          s3[wave][lane * 25 + u] = a;  // [t][u] for coalesced dump
        }
      }
      __syncthreads();
      if (alive) {
        float* outp = out + ((size_t)(n * OO + o) * TT + tile * 32) * VV;
#pragma unroll
        for (int k = 0; k < 13; ++k) {
          int idx = k * 64 + lane;
          if (idx < 800) outp[idx] = s3[wave][idx];
        }
      }
      __syncthreads();
    }
  }
}

extern "C" void kernel_launch(void* const* d_in, const int* in_sizes, int n_in,
                              void* d_out, int out_size, void* d_ws,
                              size_t ws_size, hipStream_t stream) {
  const float* x = (const float*)d_in[0];
  const float* A = (const float*)d_in[1];
  const float* w1 = (const float*)d_in[2];
  const float* b1 = (const float*)d_in[3];
  const float* w2 = (const float*)d_in[4];
  const float* b2 = (const float*)d_in[5];
  const float* w3 = (const float*)d_in[6];
  const float* b3 = (const float*)d_in[7];
  const float* w4 = (const float*)d_in[8];
  const float* b4 = (const float*)d_in[9];
  float* out = (float*)d_out;
  float* ws = (float*)d_ws;

  float* xsum = ws;          // 102400 floats
  float* w3t = ws + 102400;  // 4096 floats
  float* mp = ws + 106496;   // 3,276,800 floats (~13.5 MB total)

  k_xsum<<<NN * CC, 256, 0, stream>>>(x, xsum);
  k_build_m<<<NN, 256, 0, stream>>>(xsum, A, w1, b1, w2, b2, w4, b4, w3, w3t,
                                    mp);
  k_fused<<<dim3(8, NN), 832, 0, stream>>>(x, w3t, b3, mp, out);
}

// Round 4
// 338.986 us; speedup vs baseline: 1.1458x; 1.1458x over previous
//
#include <hip/hip_runtime.h>

#define NN 64
#define CC 64
#define TT 256
#define VV 25
#define RR 8
#define OO 64
#define PLANE 6400  // T*V per (n,c)

typedef __attribute__((ext_vector_type(8))) short short8;
typedef __attribute__((ext_vector_type(4))) float f32x4;

__device__ inline unsigned short f2bf(float f) {
  unsigned int u = __builtin_bit_cast(unsigned int, f);
  u = u + 0x7fffu + ((u >> 16) & 1u);  // RNE
  return (unsigned short)(u >> 16);
}
__device__ inline float bf2f(unsigned short h) {
  unsigned int u = ((unsigned int)h) << 16;
  return __builtin_bit_cast(float, u);
}

// ---------------------------------------------------------------------------
// k_prep: per (n, 800-p tile): read x fp32 coalesced, stage bf16 in LDS
// [p][c] (c-stride 66 shorts -> conflict-free), emit:
//   (a) xsum partials over the tile's 32 t's  -> part[n][pt][c*25+v]
//   (b) x_bf[n][p][c] (transposed, bf16) via fully-coalesced 16-B stores
// ---------------------------------------------------------------------------
__global__ __launch_bounds__(512) void k_prep(const float* __restrict__ x,
                                              unsigned short* __restrict__ xbf,
                                              float* __restrict__ part) {
  int pt = blockIdx.x;  // 0..7 (t-range pt*32..)
  int n = blockIdx.y;
  int tid = threadIdx.x;
  __shared__ unsigned short s[800 * 66];  // 105.6 KB
  const float* xn = x + (size_t)n * CC * PLANE + pt * 800;
#pragma unroll 1
  for (int i = 0; i < 25; ++i) {
    int idx4 = i * 512 + tid;  // < 12800 = 64c * 200 float4
    int c = idx4 / 200;
    int p4 = (idx4 - c * 200) * 4;
    const float4 v = *(const float4*)(xn + (size_t)c * PLANE + p4);
    s[(p4 + 0) * 66 + c] = f2bf(v.x);
    s[(p4 + 1) * 66 + c] = f2bf(v.y);
    s[(p4 + 2) * 66 + c] = f2bf(v.z);
    s[(p4 + 3) * 66 + c] = f2bf(v.w);
  }
  __syncthreads();
  // xsum partials: (c,v) threads sum 32 t's
#pragma unroll 1
  for (int i = 0; i < 4; ++i) {
    int idx = i * 512 + tid;
    if (idx < 1600) {
      int c = idx / 25, v = idx - c * 25;
      float a = 0.f;
#pragma unroll
      for (int t = 0; t < 32; ++t) a += bf2f(s[(t * 25 + v) * 66 + c]);
      part[((size_t)n * 8 + pt) * 1600 + idx] = a;
    }
  }
  // x_bf: 6400 16-B chunks (p, ch): fully coalesced dwordx4 stores
  unsigned int* dst = (unsigned int*)(xbf + ((size_t)n * PLANE + pt * 800) * 64);
#pragma unroll 1
  for (int i = 0; i < 13; ++i) {
    int idx = i * 512 + tid;
    if (idx < 6400) {
      int p = idx >> 3, ch = idx & 7;
      const unsigned int* sp = (const unsigned int*)(s + p * 66 + ch * 8);
      uint4 val;
      val.x = sp[0];
      val.y = sp[1];
      val.z = sp[2];
      val.w = sp[3];
      *(uint4*)(dst + (size_t)idx * 4) = val;
    }
  }
}

// ---------------------------------------------------------------------------
// k_build_m: reduce xsum partials, build m (fp32 [n][o][u][32] for s_load in
// k_fused), emit w3_bf[o][c] (all blocks write same values - benign).
// ---------------------------------------------------------------------------
__global__ __launch_bounds__(256) void k_build_m(
    const float* __restrict__ part, const float* __restrict__ A,
    const float* __restrict__ w1, const float* __restrict__ b1,
    const float* __restrict__ w2, const float* __restrict__ b2,
    const float* __restrict__ w4, const float* __restrict__ b4,
    const float* __restrict__ w3, unsigned short* __restrict__ w3bf,
    float* __restrict__ mp) {
  int n = blockIdx.x;
  __shared__ float xs[CC * VV];    // 1600
  __shared__ float sx1[RR * VV];   // 200
  __shared__ float sx2[RR * VV];   // 200
  __shared__ float att[RR * 625];  // 5000
  int tid = threadIdx.x;
  for (int k = tid; k < OO * CC; k += 256) w3bf[k] = f2bf(w3[k]);
  for (int k = tid; k < CC * VV; k += 256) {
    float a = 0.f;
#pragma unroll
    for (int pt = 0; pt < 8; ++pt) a += part[((size_t)n * 8 + pt) * 1600 + k];
    xs[k] = a;
  }
  __syncthreads();
  if (tid < RR * VV) {
    int r = tid / VV, v = tid % VV;
    float a1 = 0.f, a2 = 0.f;
#pragma unroll
    for (int c = 0; c < CC; ++c) {
      float xv = xs[c * VV + v];
      a1 = fmaf(w1[r * CC + c], xv, a1);
      a2 = fmaf(w2[r * CC + c], xv, a2);
    }
    sx1[tid] = a1 * (1.f / 256.f) + b1[r];
    sx2[tid] = a2 * (1.f / 256.f) + b2[r];
  }
  __syncthreads();
  for (int k = tid; k < RR * 625; k += 256) {
    int r = k / 625, uv = k % 625;
    int u = uv / VV, v = uv % VV;
    att[k] = tanhf(sx1[r * VV + u] - sx2[r * VV + v]);
  }
  __syncthreads();
  for (int k = tid; k < OO * 625; k += 256) {
    int o = k / 625, uv = k % 625;
    int u = uv / VV, v = uv % VV;
    float a = b4[o] + A[uv];
#pragma unroll
    for (int r = 0; r < RR; ++r) a = fmaf(w4[o * RR + r], att[r * 625 + uv], a);
    mp[((size_t)(n * OO + o) * VV + u) * 32 + v] = a;
  }
}

// ---------------------------------------------------------------------------
// k_fused: block = (n, 64-t tile -> 1600 p), 512 threads (8 waves),
// 2 o-chunks of 32.
//  GEMM1 (MFMA 16x16x32 bf16): x3[o][p] = sum_c w3[o][c] x_bf[p][c].
//   A-frag: w3bf[o=lane&15][c=q*8+j] (preloaded). B-frag: x_bf direct 16-B
//   global loads. D (col=p=lane&15, row=o=q*4+reg) -> bf16 -> x3s LDS
//   (row stride 1602 shorts: quads land 4 dwords apart -> <=2-way banks).
//  Aggregation (VALU, full 64 lanes): lane=t; o wave-uniform -> m rows via
//   s_load; out[t][u] = sum_v m[u][v]*(x3[t][v]+b3[o]); transpose through
//   per-wave tbuf, coalesced 256-B dumps.
// ---------------------------------------------------------------------------
__global__ __launch_bounds__(512, 1) void k_fused(
    const unsigned short* __restrict__ xbf,
    const unsigned short* __restrict__ w3bf, const float* __restrict__ b3,
    const float* __restrict__ mp, float* __restrict__ out) {
  int ttile = blockIdx.x;  // 0..3
  int n = blockIdx.y;
  int tid = threadIdx.x;
  int lane = tid & 63, wave = tid >> 6;
  int l15 = lane & 15, q = lane >> 4;
  __shared__ unsigned short x3s[32 * 1602];  // 102.5 KB
  __shared__ float tbuf[8][1600];            // 51.2 KB
  const unsigned short* xbn = xbf + ((size_t)n * PLANE + ttile * 1600) * 64;

#pragma unroll 1
  for (int chunk = 0; chunk < 2; ++chunk) {
    // preload A-fragments (w3 rows for this o-chunk)
    short8 afr[2][2];
#pragma unroll
    for (int ot = 0; ot < 2; ++ot)
#pragma unroll
      for (int q2 = 0; q2 < 2; ++q2)
        afr[ot][q2] = *(const short8*)(w3bf + (chunk * 32 + ot * 16 + l15) * 64 +
                                       q2 * 32 + q * 8);
    // ---- GEMM1 ----
#pragma unroll 1
    for (int i = 0; i < 13; ++i) {
      int pt = i * 8 + wave;
      if (pt < 100) {
        const unsigned short* bp = xbn + (size_t)(pt * 16 + l15) * 64 + q * 8;
        short8 b0 = *(const short8*)(bp);
        short8 b1 = *(const short8*)(bp + 32);
        int p_loc = pt * 16 + l15;
#pragma unroll
        for (int ot = 0; ot < 2; ++ot) {
          f32x4 d = {0.f, 0.f, 0.f, 0.f};
          d = __builtin_amdgcn_mfma_f32_16x16x32_bf16(afr[ot][0], b0, d, 0, 0, 0);
          d = __builtin_amdgcn_mfma_f32_16x16x32_bf16(afr[ot][1], b1, d, 0, 0, 0);
          int orow = ot * 16 + q * 4;
#pragma unroll
          for (int r = 0; r < 4; ++r)
            x3s[(orow + r) * 1602 + p_loc] = f2bf(d[r]);
        }
      }
    }
    __syncthreads();
    // ---- aggregation ----
#pragma unroll 1
    for (int j = 0; j < 4; ++j) {
      int ol = wave * 4 + j;
      int o = __builtin_amdgcn_readfirstlane(chunk * 32 + ol);
      const float* mrow = mp + ((size_t)(n * OO + o) * VV) * 32;  // uniform
      float b3o = b3[o];
      int t = lane;
      float xr[VV];
#pragma unroll
      for (int v = 0; v < VV; ++v)
        xr[v] = bf2f(x3s[ol * 1602 + t * 25 + v]) + b3o;
      float* tb = tbuf[wave];
#pragma unroll
      for (int u = 0; u < VV; ++u) {
        float a = 0.f;
#pragma unroll
        for (int v = 0; v < VV; ++v) a = fmaf(mrow[u * 32 + v], xr[v], a);
        tb[t * 25 + u] = a;
      }
      float* op = out + ((size_t)(n * OO + o) * TT + ttile * 64) * VV;
#pragma unroll
      for (int k = 0; k < 25; ++k) op[k * 64 + lane] = tb[k * 64 + lane];
    }
    __syncthreads();
  }
}

extern "C" void kernel_launch(void* const* d_in, const int* in_sizes, int n_in,
                              void* d_out, int out_size, void* d_ws,
                              size_t ws_size, hipStream_t stream) {
  const float* x = (const float*)d_in[0];
  const float* A = (const float*)d_in[1];
  const float* w1 = (const float*)d_in[2];
  const float* b1 = (const float*)d_in[3];
  const float* w2 = (const float*)d_in[4];
  const float* b2 = (const float*)d_in[5];
  const float* w3 = (const float*)d_in[6];
  const float* b3 = (const float*)d_in[7];
  const float* w4 = (const float*)d_in[8];
  const float* b4 = (const float*)d_in[9];
  float* out = (float*)d_out;
  char* ws = (char*)d_ws;

  // ws layout (bytes): x_bf 52,428,800 | part 3,276,800 | mp 13,107,200 |
  // w3bf 8,192  => total 68,820,992
  unsigned short* xbf = (unsigned short*)ws;
  float* part = (float*)(ws + 52428800);
  float* mp = (float*)(ws + 55705600);
  unsigned short* w3bf = (unsigned short*)(ws + 68812800);

  k_prep<<<dim3(8, NN), 512, 0, stream>>>(x, xbf, part);
  k_build_m<<<NN, 256, 0, stream>>>(part, A, w1, b1, w2, b2, w4, b4, w3, w3bf,
                                    mp);
  k_fused<<<dim3(4, NN), 512, 0, stream>>>(xbf, w3bf, b3, mp, out);
}